// Round 2
// baseline (1152.905 us; speedup 1.0000x reference)
//
#include <hip/hip_runtime.h>
#include <hip/hip_bf16.h>

// Problem: B=2 H=16 S=2048 D=64, fp32 in, outputs (output[B,H,S,D], attn[B,H,S,S]) fp32.
// attn = softmax(where(mask, -1e9, (q/8)@k^T)) * new_mask ; output = attn @ v
// Strategy: per (b,h,64-q-rows) workgroup, 2 passes over 64-wide K tiles.
// Pass1: bf16 MFMA QK^T + mask -> online row max m / sumexp l.
// Pass2: recompute scores, p=exp(s-m)/l * new_mask -> write attn, P@V via MFMA.

#define Bsz 2
#define Hn 16
#define Sn 2048
#define Dn 64
#define NEG_INF -1000000000.0f

typedef __attribute__((ext_vector_type(8))) short bf16x8;
typedef __attribute__((ext_vector_type(4))) float f32x4;

__device__ __forceinline__ unsigned short f2bf(float x) {
  unsigned u = __builtin_bit_cast(unsigned, x);
  u += 0x7fffu + ((u >> 16) & 1u);   // RNE
  return (unsigned short)(u >> 16);
}

__device__ __forceinline__ bf16x8 lds8(const unsigned short* p) {
  union { ushort4 h[2]; bf16x8 v; } u;
  u.h[0] = *(const ushort4*)p;
  u.h[1] = *(const ushort4*)(p + 4);
  return u.v;
}

__global__ __launch_bounds__(256, 4) void attn_fused(
    const float* __restrict__ qg, const float* __restrict__ kg,
    const float* __restrict__ vg, const float* __restrict__ nmg,
    const int* __restrict__ mg, float* __restrict__ outg)
{
  __shared__ unsigned short qs[64][72];   // Q tile bf16 (pre-scaled 1/8), +8 pad
  __shared__ unsigned short ks[64][72];   // K tile bf16 [k_row][d]
  __shared__ unsigned short vts[64][72];  // V tile bf16 TRANSPOSED [d][k_row]
  __shared__ unsigned short ps[4][16][72];// per-wave P tile bf16 [qrow][k_col]

  const int tid = threadIdx.x;
  const int wv = tid >> 6;
  const int lane = tid & 63;
  const int lg = lane >> 4, li = lane & 15;
  const int qb = blockIdx.x * 64;
  const int h = blockIdx.y, b = blockIdx.z;

  const float* qp  = qg + (size_t)(b*Hn + h) * Sn * Dn;
  const float* kp  = kg + (size_t)(b*Hn + h) * Sn * Dn;
  const float* vp  = vg + (size_t)(b*Hn + h) * Sn * Dn;
  const float* nmb = nmg + (size_t)b * Sn * Sn;          // new_mask [B,1,S,S]
  const int*   mb  = mg  + (size_t)b * Sn * Sn;          // mask     [B,1,S,S] as int32
  float* outO = outg + (size_t)(b*Hn + h) * Sn * Dn;
  float* outA = outg + (size_t)Bsz*Hn*Sn*Dn + (size_t)(b*Hn + h) * Sn * Sn;

  // ---- stage Q (x 1/8 -> bf16) ----
  #pragma unroll
  for (int i = 0; i < 4; ++i) {
    int slot = tid + i*256;
    int r = slot >> 4, c = (slot & 15) << 2;
    float4 f = *(const float4*)(qp + (size_t)(qb + r)*Dn + c);
    ushort4 u = { f2bf(f.x*0.125f), f2bf(f.y*0.125f), f2bf(f.z*0.125f), f2bf(f.w*0.125f) };
    *(ushort4*)&qs[r][c] = u;
  }
  __syncthreads();
  // A-frags for this wave's 16 q-rows (kept all kernel):
  // A[m][k]: m = li, k = lg*8+j (+32 for second half of D)
  bf16x8 aq0 = lds8(&qs[wv*16 + li][lg*8]);
  bf16x8 aq1 = lds8(&qs[wv*16 + li][32 + lg*8]);

  float mr[4] = {-INFINITY, -INFINITY, -INFINITY, -INFINITY};
  float lr[4] = {0.f, 0.f, 0.f, 0.f};

  // ================= pass 1: row stats =================
  for (int k0 = 0; k0 < Sn; k0 += 64) {
    __syncthreads();
    #pragma unroll
    for (int i = 0; i < 4; ++i) {
      int slot = tid + i*256;
      int r = slot >> 4, c = (slot & 15) << 2;
      float4 f = *(const float4*)(kp + (size_t)(k0 + r)*Dn + c);
      ushort4 u = { f2bf(f.x), f2bf(f.y), f2bf(f.z), f2bf(f.w) };
      *(ushort4*)&ks[r][c] = u;
    }
    __syncthreads();

    f32x4 acc[4];
    #pragma unroll
    for (int n = 0; n < 4; ++n) { f32x4 z = {0.f,0.f,0.f,0.f}; acc[n] = z; }
    #pragma unroll
    for (int n = 0; n < 4; ++n) {
      acc[n] = __builtin_amdgcn_mfma_f32_16x16x32_bf16(aq0, lds8(&ks[n*16+li][lg*8]),    acc[n], 0, 0, 0);
      acc[n] = __builtin_amdgcn_mfma_f32_16x16x32_bf16(aq1, lds8(&ks[n*16+li][32+lg*8]), acc[n], 0, 0, 0);
    }
    // C/D layout: row = lg*4 + r, col = n*16 + li
    #pragma unroll
    for (int r = 0; r < 4; ++r) {
      int grow = qb + wv*16 + lg*4 + r;
      const int* mp = mb + (size_t)grow*Sn + k0 + li;
      float s0 = mp[0]  ? NEG_INF : acc[0][r];
      float s1 = mp[16] ? NEG_INF : acc[1][r];
      float s2 = mp[32] ? NEG_INF : acc[2][r];
      float s3 = mp[48] ? NEG_INF : acc[3][r];
      float tmax = fmaxf(fmaxf(s0, s1), fmaxf(s2, s3));
      #pragma unroll
      for (int d2 = 1; d2 < 16; d2 <<= 1) tmax = fmaxf(tmax, __shfl_xor(tmax, d2));
      float mn = fmaxf(mr[r], tmax);
      float se = __expf(s0 - mn) + __expf(s1 - mn) + __expf(s2 - mn) + __expf(s3 - mn);
      #pragma unroll
      for (int d2 = 1; d2 < 16; d2 <<= 1) se += __shfl_xor(se, d2);
      lr[r] = lr[r] * __expf(mr[r] - mn) + se;
      mr[r] = mn;
    }
  }

  float il[4];
  #pragma unroll
  for (int r = 0; r < 4; ++r) il[r] = 1.0f / lr[r];

  f32x4 oa[4];
  #pragma unroll
  for (int n = 0; n < 4; ++n) { f32x4 z = {0.f,0.f,0.f,0.f}; oa[n] = z; }

  // ================= pass 2: attn write + PV =================
  for (int k0 = 0; k0 < Sn; k0 += 64) {
    __syncthreads();
    #pragma unroll
    for (int i = 0; i < 4; ++i) {
      int slot = tid + i*256;
      int r = slot >> 4, c = (slot & 15) << 2;
      float4 f = *(const float4*)(kp + (size_t)(k0 + r)*Dn + c);
      ushort4 u = { f2bf(f.x), f2bf(f.y), f2bf(f.z), f2bf(f.w) };
      *(ushort4*)&ks[r][c] = u;
      float4 g = *(const float4*)(vp + (size_t)(k0 + r)*Dn + c);
      vts[c+0][r] = f2bf(g.x);
      vts[c+1][r] = f2bf(g.y);
      vts[c+2][r] = f2bf(g.z);
      vts[c+3][r] = f2bf(g.w);
    }
    __syncthreads();

    f32x4 acc[4];
    #pragma unroll
    for (int n = 0; n < 4; ++n) { f32x4 z = {0.f,0.f,0.f,0.f}; acc[n] = z; }
    #pragma unroll
    for (int n = 0; n < 4; ++n) {
      acc[n] = __builtin_amdgcn_mfma_f32_16x16x32_bf16(aq0, lds8(&ks[n*16+li][lg*8]),    acc[n], 0, 0, 0);
      acc[n] = __builtin_amdgcn_mfma_f32_16x16x32_bf16(aq1, lds8(&ks[n*16+li][32+lg*8]), acc[n], 0, 0, 0);
    }
    #pragma unroll
    for (int r = 0; r < 4; ++r) {
      int grow = qb + wv*16 + lg*4 + r;
      const size_t rowo = (size_t)grow*Sn + k0 + li;
      const int* mp = mb + rowo;
      const float* nmp = nmb + rowo;
      float* ap = outA + rowo;
      #pragma unroll
      for (int n = 0; n < 4; ++n) {
        float p = mp[n*16] ? 0.f : __expf(acc[n][r] - mr[r]) * il[r];
        float a = p * nmp[n*16];
        ap[n*16] = a;
        ps[wv][lg*4 + r][n*16 + li] = f2bf(a);
      }
    }
    // wave-local: ensure ps writes visible before re-fragmenting (same wave only)
    asm volatile("s_waitcnt lgkmcnt(0)" ::: "memory");
    #pragma unroll
    for (int kk = 0; kk < 2; ++kk) {
      bf16x8 ap8 = lds8(&ps[wv][li][kk*32 + lg*8]);   // A[m=li][k]
      #pragma unroll
      for (int n2 = 0; n2 < 4; ++n2) {
        oa[n2] = __builtin_amdgcn_mfma_f32_16x16x32_bf16(
            ap8, lds8(&vts[n2*16 + li][kk*32 + lg*8]), oa[n2], 0, 0, 0);
      }
    }
  }

  // ---- epilogue: write O ----
  #pragma unroll
  for (int n2 = 0; n2 < 4; ++n2) {
    #pragma unroll
    for (int r = 0; r < 4; ++r) {
      outO[(size_t)(qb + wv*16 + lg*4 + r)*Dn + n2*16 + li] = oa[n2][r];
    }
  }
}

extern "C" void kernel_launch(void* const* d_in, const int* in_sizes, int n_in,
                              void* d_out, int out_size, void* d_ws, size_t ws_size,
                              hipStream_t stream) {
  const float* q  = (const float*)d_in[0];
  const float* k  = (const float*)d_in[1];
  const float* v  = (const float*)d_in[2];
  const float* nm = (const float*)d_in[3];
  const int*   m  = (const int*)d_in[4];
  float* out = (float*)d_out;
  dim3 grid(Sn / 64, Hn, Bsz);
  attn_fused<<<grid, dim3(256), 0, stream>>>(q, k, v, nm, m, out);
}